// Round 9
// baseline (224.640 us; speedup 1.0000x reference)
//
#include <hip/hip_runtime.h>
#include <hip/hip_bf16.h>
#include <cstdint>
#include <cstddef>

#define BATCH 256
#define NGO   8000
#define NKE   2000
#define DD    16
#define XCOLS 10048
#define NDRUG 2048
#define NT    512
#define NSLAB 8
#define SB    32            // batch per slab
#define TANH_SCALE 2.885390081777926f   // 2/ln2

// tanh(z) = 1 - 2/(exp(2z)+1) with bare v_exp_f32 + v_rcp_f32.
__device__ __forceinline__ float tanh_fast(float z) {
    float e = __builtin_amdgcn_exp2f(z * TANH_SCALE);
    float r = __builtin_amdgcn_rcpf(e + 1.0f);
    return fmaf(-2.0f, r, 1.0f);
}

// r = 1/(exp2(zp)+1) where zp is already scaled by 2/ln2.
__device__ __forceinline__ float rcp_core(float zp) {
    float e = __builtin_amdgcn_exp2f(zp);
    return __builtin_amdgcn_rcpf(e + 1.0f);
}

__device__ __forceinline__ void add4(float4& a, const float4 b) {
    a.x += b.x; a.y += b.y; a.z += b.z; a.w += b.w;
}

#define RFL(v) __builtin_amdgcn_readfirstlane(v)

// ---------------- CSR scan ----------------
__global__ void k_scan2(const int* __restrict__ cnt_go, const int* __restrict__ cnt_kk,
                        int* __restrict__ rp_go, int* __restrict__ rp_kk) {
    const int* cnt = blockIdx.x ? cnt_kk : cnt_go;
    int* rowptr    = blockIdx.x ? rp_kk  : rp_go;
    __shared__ int s[2048];
    int t = threadIdx.x;
    s[t]        = (t        < NKE) ? cnt[t]        : 0;
    s[t + 1024] = (t + 1024 < NKE) ? cnt[t + 1024] : 0;
    __syncthreads();
    for (int st = 1; st < 2048; st <<= 1) {
        int v0 = (t >= st) ? s[t - st] : 0;
        int v1 = s[t + 1024 - st];
        __syncthreads();
        s[t] += v0; s[t + 1024] += v1;
        __syncthreads();
    }
    if (t == 0) rowptr[0] = 0;
    rowptr[t + 1] = s[t];
    if (t + 1024 < NKE) rowptr[t + 1025] = s[t + 1024];
}

__global__ void k_fill2(const int* __restrict__ gs, const int* __restrict__ gdst,
                        const int* __restrict__ ks, const int* __restrict__ kdst,
                        int Eg, int Ek,
                        const int* __restrict__ rp_go, int* __restrict__ cur_go, int* __restrict__ col_go,
                        const int* __restrict__ rp_kk, int* __restrict__ cur_kk, int* __restrict__ col_kk) {
    int e = blockIdx.x * 256 + threadIdx.x;
    if (e < Eg) {
        int d = gdst[e];
        int p = atomicAdd(&cur_go[d], 1);
        col_go[rp_go[d] + p] = gs[e];
    } else if (e < Eg + Ek) {
        int e2 = e - Eg;
        int d = kdst[e2];
        int p = atomicAdd(&cur_kk[d], 1);
        col_kk[rp_kk[d] + p] = ks[e2];
    }
}

// ---------------- prep: transposes + bd prescale + edge histograms ----------------
__global__ __launch_bounds__(256) void k_prep(const float* __restrict__ x,
                                              float* __restrict__ xT,
                                              float* __restrict__ xdT,
                                              const float* __restrict__ bd,
                                              float* __restrict__ bds,
                                              const int* __restrict__ gdst,
                                              const int* __restrict__ kdst,
                                              int* __restrict__ cnt_go,
                                              int* __restrict__ cnt_kk,
                                              int Eg, int Ek) {
    int bid = blockIdx.x;
    if (bid >= 1128) {
        int e = (bid - 1128) * 256 + threadIdx.x;
        if (e < Eg) atomicAdd(&cnt_go[gdst[e]], 1);
        else if (e < Eg + Ek) atomicAdd(&cnt_kk[kdst[e - Eg]], 1);
        return;
    }
    if (bid >= 628) {
        int i = (bid - 628) * 256 + threadIdx.x;
        bds[i] = bd[i] * TANH_SCALE;
        return;
    }
    __shared__ float tile[64][69];
    int c4 = threadIdx.x & 15, rr = threadIdx.x >> 4;
    int n0, b0;
    bool isgo = bid < 500;
    if (isgo) { n0 = (bid % 125) * 64; b0 = (bid / 125) * 64; }
    else      { int t = bid - 500; n0 = NGO + (t & 31) * 64; b0 = (t >> 5) * 64; }
#pragma unroll
    for (int i = 0; i < 4; i++) {
        int row = rr + i * 16;
        float4 v = *(const float4*)&x[(size_t)(b0 + row) * XCOLS + n0 + c4 * 4];
        tile[row][c4 * 4 + 0] = v.x; tile[row][c4 * 4 + 1] = v.y;
        tile[row][c4 * 4 + 2] = v.z; tile[row][c4 * 4 + 3] = v.w;
    }
    __syncthreads();
#pragma unroll
    for (int i = 0; i < 4; i++) {
        int nrow = rr + i * 16;
        float4 w;
        w.x = tile[c4 * 4 + 0][nrow]; w.y = tile[c4 * 4 + 1][nrow];
        w.z = tile[c4 * 4 + 2][nrow]; w.w = tile[c4 * 4 + 3][nrow];
        if (isgo) {
            w.x *= TANH_SCALE; w.y *= TANH_SCALE; w.z *= TANH_SCALE; w.w *= TANH_SCALE;
            *(float4*)&xT[(size_t)(n0 + nrow) * 256 + b0 + c4 * 4] = w;
        } else {
            *(float4*)&xdT[(size_t)(n0 - NGO + nrow) * 256 + b0 + c4 * 4] = w;
        }
    }
}

// ---------------- fused decode + GO->KE scatter + transform ----------------
// All gather bases forced into SGPRs via readfirstlane (wave-uniform cols).
__global__ __launch_bounds__(128) void k_fuse(const float* __restrict__ xT,
                                              const int* __restrict__ rowptr,
                                              const int* __restrict__ col,
                                              const float* __restrict__ Wd,
                                              const float* __restrict__ bds,
                                              const float* __restrict__ W,
                                              const float* __restrict__ bias,
                                              float* __restrict__ ke) {
    __shared__ float pre[32 * 17];
    __shared__ float Ws[256];
    __shared__ float bs[16];
    int s = blockIdx.x & 7, n = blockIdx.x >> 3;
    int tid = threadIdx.x;
    Ws[tid] = W[tid]; Ws[tid + 128] = W[tid + 128];
    if (tid < 16) bs[tid] = bias[tid];
    int bloc = tid >> 2, d4 = tid & 3;
    int bglob = s * SB + bloc;

    int e   = RFL(rowptr[n]);
    int end = RFL(rowptr[n + 1]);
    float degF = (float)(end - e);
    float4 acc = make_float4(0, 0, 0, 0);
    for (; e + 3 < end; e += 4) {
        int s0 = RFL(col[e]);
        int s1 = RFL(col[e + 1]);
        int s2 = RFL(col[e + 2]);
        int s3 = RFL(col[e + 3]);
        float xv0 = (xT + (size_t)s0 * 256)[bglob];
        float xv1 = (xT + (size_t)s1 * 256)[bglob];
        float xv2 = (xT + (size_t)s2 * 256)[bglob];
        float xv3 = (xT + (size_t)s3 * 256)[bglob];
        float4 w0 = *(const float4*)(Wd  + (size_t)s0 * 16 + d4 * 4);
        float4 w1 = *(const float4*)(Wd  + (size_t)s1 * 16 + d4 * 4);
        float4 w2 = *(const float4*)(Wd  + (size_t)s2 * 16 + d4 * 4);
        float4 w3 = *(const float4*)(Wd  + (size_t)s3 * 16 + d4 * 4);
        float4 c0 = *(const float4*)(bds + (size_t)s0 * 16 + d4 * 4);
        float4 c1 = *(const float4*)(bds + (size_t)s1 * 16 + d4 * 4);
        float4 c2 = *(const float4*)(bds + (size_t)s2 * 16 + d4 * 4);
        float4 c3 = *(const float4*)(bds + (size_t)s3 * 16 + d4 * 4);
        acc.x += rcp_core(fmaf(xv0, w0.x, c0.x)) + rcp_core(fmaf(xv1, w1.x, c1.x))
               + rcp_core(fmaf(xv2, w2.x, c2.x)) + rcp_core(fmaf(xv3, w3.x, c3.x));
        acc.y += rcp_core(fmaf(xv0, w0.y, c0.y)) + rcp_core(fmaf(xv1, w1.y, c1.y))
               + rcp_core(fmaf(xv2, w2.y, c2.y)) + rcp_core(fmaf(xv3, w3.y, c3.y));
        acc.z += rcp_core(fmaf(xv0, w0.z, c0.z)) + rcp_core(fmaf(xv1, w1.z, c1.z))
               + rcp_core(fmaf(xv2, w2.z, c2.z)) + rcp_core(fmaf(xv3, w3.z, c3.z));
        acc.w += rcp_core(fmaf(xv0, w0.w, c0.w)) + rcp_core(fmaf(xv1, w1.w, c1.w))
               + rcp_core(fmaf(xv2, w2.w, c2.w)) + rcp_core(fmaf(xv3, w3.w, c3.w));
    }
    for (; e < end; ++e) {
        int s0 = RFL(col[e]);
        float xv0 = (xT + (size_t)s0 * 256)[bglob];
        float4 w0 = *(const float4*)(Wd  + (size_t)s0 * 16 + d4 * 4);
        float4 c0 = *(const float4*)(bds + (size_t)s0 * 16 + d4 * 4);
        acc.x += rcp_core(fmaf(xv0, w0.x, c0.x));
        acc.y += rcp_core(fmaf(xv0, w0.y, c0.y));
        acc.z += rcp_core(fmaf(xv0, w0.z, c0.z));
        acc.w += rcp_core(fmaf(xv0, w0.w, c0.w));
    }
    pre[bloc * 17 + d4 * 4 + 0] = fmaf(-2.0f, acc.x, degF);
    pre[bloc * 17 + d4 * 4 + 1] = fmaf(-2.0f, acc.y, degF);
    pre[bloc * 17 + d4 * 4 + 2] = fmaf(-2.0f, acc.z, degF);
    pre[bloc * 17 + d4 * 4 + 3] = fmaf(-2.0f, acc.w, degF);
    __syncthreads();

    float4 o;
    float* op = &o.x;
#pragma unroll
    for (int q = 0; q < 4; q++) {
        int dp = d4 * 4 + q;
        float a = bs[dp];
#pragma unroll
        for (int d = 0; d < 16; d++) a = fmaf(pre[bloc * 17 + d], Ws[d * 16 + dp], a);
        op[q] = tanh_fast(a);
    }
    *(float4*)&ke[((size_t)s * NKE + n) * 512 + bloc * 16 + d4 * 4] = o;
}

// ---------------- KE-KE layer, slab layout, scalarized gather bases ----------------
__global__ __launch_bounds__(128) void k_layer(const float* __restrict__ kin,
                                               const int* __restrict__ rowptr,
                                               const int* __restrict__ col,
                                               const float* __restrict__ W,
                                               const float* __restrict__ bias,
                                               float* __restrict__ kout) {
    __shared__ float pre[32 * 17];
    __shared__ float Ws[256];
    __shared__ float bs[16];
    int s = blockIdx.x & 7, n = blockIdx.x >> 3;
    int tid = threadIdx.x;
    Ws[tid] = W[tid]; Ws[tid + 128] = W[tid + 128];
    if (tid < 16) bs[tid] = bias[tid];
    int bloc = tid >> 2, d4 = tid & 3;
    const float* slab = kin + (size_t)s * NKE * 512;

    float4 acc = *(const float4*)(slab + (size_t)n * 512 + tid * 4);
    int e   = RFL(rowptr[n]);
    int end = RFL(rowptr[n + 1]);
    for (; e + 3 < end; e += 4) {
        int c0 = RFL(col[e]), c1 = RFL(col[e + 1]), c2 = RFL(col[e + 2]), c3 = RFL(col[e + 3]);
        float4 v0 = *(const float4*)(slab + (size_t)c0 * 512 + tid * 4);
        float4 v1 = *(const float4*)(slab + (size_t)c1 * 512 + tid * 4);
        float4 v2 = *(const float4*)(slab + (size_t)c2 * 512 + tid * 4);
        float4 v3 = *(const float4*)(slab + (size_t)c3 * 512 + tid * 4);
        add4(acc, v0); add4(acc, v1); add4(acc, v2); add4(acc, v3);
    }
    for (; e < end; ++e) {
        int c0 = RFL(col[e]);
        float4 v0 = *(const float4*)(slab + (size_t)c0 * 512 + tid * 4);
        add4(acc, v0);
    }
    pre[bloc * 17 + d4 * 4 + 0] = acc.x;
    pre[bloc * 17 + d4 * 4 + 1] = acc.y;
    pre[bloc * 17 + d4 * 4 + 2] = acc.z;
    pre[bloc * 17 + d4 * 4 + 3] = acc.w;
    __syncthreads();

    float4 o;
    float* op = &o.x;
#pragma unroll
    for (int q = 0; q < 4; q++) {
        int dp = d4 * 4 + q;
        float a = bs[dp];
#pragma unroll
        for (int d = 0; d < 16; d++) a = fmaf(pre[bloc * 17 + d], Ws[d * 16 + dp], a);
        op[q] = tanh_fast(a);
    }
    *(float4*)&kout[(size_t)s * NKE * 512 + (size_t)n * 512 + bloc * 16 + d4 * 4] = o;
}

// ---------------- tissue readout ----------------
__global__ __launch_bounds__(256) void k_kescalar(const float* __restrict__ ke,
                                                  const int* __restrict__ tissue,
                                                  const float* __restrict__ wke,
                                                  const float* __restrict__ bke,
                                                  float* __restrict__ bioT) {
    int t = blockIdx.x, b = threadIdx.x;
    int n = RFL(tissue[t]);
    int s = b >> 5, bloc = b & 31;
    const float4* kp = (const float4*)&ke[((size_t)s * NKE + n) * 512 + bloc * 16];
    const float4* wp = (const float4*)wke;
    float4 k0 = kp[0], k1 = kp[1], k2 = kp[2], k3 = kp[3];
    float4 w0 = wp[0], w1 = wp[1], w2 = wp[2], w3 = wp[3];
    float acc = bke[0];
    acc += k0.x * w0.x + k0.y * w0.y + k0.z * w0.z + k0.w * w0.w;
    acc += k1.x * w1.x + k1.y * w1.y + k1.z * w1.z + k1.w * w1.w;
    acc += k2.x * w2.x + k2.y * w2.y + k2.z * w2.z + k2.w * w2.w;
    acc += k3.x * w3.x + k3.y * w3.y + k3.z * w3.z + k3.w * w3.w;
    bioT[t * 256 + b] = tanh_fast(acc);
}

// ---------------- tiled GEMM + split-K ----------------
__global__ __launch_bounds__(256) void k_gemm(const float* __restrict__ A,
                                              const float* __restrict__ W,
                                              float* __restrict__ Cpart,
                                              int N, int Kper) {
    __shared__ float As[32][68];
    __shared__ float Ws[32][68];
    int tid = threadIdx.x;
    int tx = tid & 15, ty = tid >> 4;
    int jt = blockIdx.x * 64, bt = blockIdx.y * 64;
    int ks = blockIdx.z;
    int k0 = ks * Kper;

    float acc[4][4];
#pragma unroll
    for (int i = 0; i < 4; i++)
#pragma unroll
        for (int j = 0; j < 4; j++) acc[i][j] = 0.0f;

    for (int kc = 0; kc < Kper; kc += 32) {
#pragma unroll
        for (int i = 0; i < 8; i++) {
            int idx = tid + i * 256;
            int kk = idx >> 6, cc = idx & 63;
            As[kk][cc] = A[(size_t)(k0 + kc + kk) * 256 + bt + cc];
            Ws[kk][cc] = W[(size_t)(k0 + kc + kk) * N + jt + cc];
        }
        __syncthreads();
#pragma unroll 8
        for (int kk = 0; kk < 32; kk++) {
            float4 a = *(const float4*)&As[kk][tx * 4];
            float4 w = *(const float4*)&Ws[kk][ty * 4];
            acc[0][0] = fmaf(w.x, a.x, acc[0][0]); acc[0][1] = fmaf(w.x, a.y, acc[0][1]);
            acc[0][2] = fmaf(w.x, a.z, acc[0][2]); acc[0][3] = fmaf(w.x, a.w, acc[0][3]);
            acc[1][0] = fmaf(w.y, a.x, acc[1][0]); acc[1][1] = fmaf(w.y, a.y, acc[1][1]);
            acc[1][2] = fmaf(w.y, a.z, acc[1][2]); acc[1][3] = fmaf(w.y, a.w, acc[1][3]);
            acc[2][0] = fmaf(w.z, a.x, acc[2][0]); acc[2][1] = fmaf(w.z, a.y, acc[2][1]);
            acc[2][2] = fmaf(w.z, a.z, acc[2][2]); acc[2][3] = fmaf(w.z, a.w, acc[2][3]);
            acc[3][0] = fmaf(w.w, a.x, acc[3][0]); acc[3][1] = fmaf(w.w, a.y, acc[3][1]);
            acc[3][2] = fmaf(w.w, a.z, acc[3][2]); acc[3][3] = fmaf(w.w, a.w, acc[3][3]);
        }
        __syncthreads();
    }
#pragma unroll
    for (int jy = 0; jy < 4; jy++) {
        int j = jt + ty * 4 + jy;
        float4 v = make_float4(acc[jy][0], acc[jy][1], acc[jy][2], acc[jy][3]);
        *(float4*)&Cpart[((size_t)ks * N + j) * 256 + bt + tx * 4] = v;
    }
}

__global__ __launch_bounds__(256) void k_red(const float* __restrict__ Cpart,
                                             const float* __restrict__ bias,
                                             float* __restrict__ C, int N, int S) {
    int j = blockIdx.x, b = threadIdx.x;
    float acc = bias[j];
    for (int s = 0; s < S; s++) acc += Cpart[((size_t)s * N + j) * 256 + b];
    C[j * 256 + b] = fmaxf(acc, 0.0f);
}

// ---------------- final head ----------------
__global__ __launch_bounds__(256) void k_final(const float* __restrict__ bio2T,
                                               const float* __restrict__ drug2T,
                                               const float* __restrict__ Wp,
                                               const float* __restrict__ bp,
                                               float* __restrict__ out) {
    int b = threadIdx.x;
    float acc = bp[0];
#pragma unroll 8
    for (int i = 0; i < 128; i++) acc = fmaf(bio2T[i * 256 + b], Wp[i], acc);
#pragma unroll 8
    for (int i = 0; i < 128; i++) acc = fmaf(drug2T[i * 256 + b], Wp[128 + i], acc);
    out[b] = acc;
}

extern "C" void kernel_launch(void* const* d_in, const int* in_sizes, int n_in,
                              void* d_out, int out_size, void* d_ws, size_t ws_size,
                              hipStream_t stream) {
    const float* x       = (const float*)d_in[0];
    const int*   go_src  = (const int*)d_in[1];
    const int*   go_dst  = (const int*)d_in[2];
    const int*   kk_src  = (const int*)d_in[3];
    const int*   kk_dst  = (const int*)d_in[4];
    const int*   tissue  = (const int*)d_in[5];
    const float* W_dec   = (const float*)d_in[6];
    const float* b_dec   = (const float*)d_in[7];
    const float* W_g2k   = (const float*)d_in[8];
    const float* b_g2k   = (const float*)d_in[9];
    const float* W_kk    = (const float*)d_in[10];
    const float* b_kk    = (const float*)d_in[11];
    const float* w_ke    = (const float*)d_in[12];
    const float* b_ke    = (const float*)d_in[13];
    const float* W_bio1  = (const float*)d_in[14];
    const float* b_bio1  = (const float*)d_in[15];
    const float* W_bio2  = (const float*)d_in[16];
    const float* b_bio2  = (const float*)d_in[17];
    const float* W_drug1 = (const float*)d_in[18];
    const float* b_drug1 = (const float*)d_in[19];
    const float* W_drug2 = (const float*)d_in[20];
    const float* b_drug2 = (const float*)d_in[21];
    const float* W_pred  = (const float*)d_in[22];
    const float* b_pred  = (const float*)d_in[23];
    float* out = (float*)d_out;

    const int E_GO = in_sizes[1];
    const int E_KK = in_sizes[3];

    char* wsb = (char*)d_ws;
    size_t off = 0;
    float* xT      = (float*)(wsb + off); off += (size_t)NGO * 256 * 4;
    float* ke_a    = (float*)(wsb + off); off += (size_t)NSLAB * NKE * 512 * 4;
    float* ke_b    = (float*)(wsb + off); off += (size_t)NSLAB * NKE * 512 * 4;
    float* bio_inT = (float*)(wsb + off); off += (size_t)NT * 256 * 4;
    float* bio1T   = (float*)(wsb + off); off += (size_t)256 * 256 * 4;
    float* bio2T   = (float*)(wsb + off); off += (size_t)128 * 256 * 4;
    float* xdT     = (float*)(wsb + off); off += (size_t)NDRUG * 256 * 4;
    float* drug1T  = (float*)(wsb + off); off += (size_t)512 * 256 * 4;
    float* drug2T  = (float*)(wsb + off); off += (size_t)128 * 256 * 4;
    float* bds     = (float*)(wsb + off); off += (size_t)NGO * 16 * 4;
    float* cpart   = (float*)(wsb + off); off += (size_t)8 * 512 * 256 * 4;
    int* cnt_go    = (int*)(wsb + off); off += 2048 * 4;
    int* cur_go    = (int*)(wsb + off); off += 2048 * 4;
    int* cnt_kk    = (int*)(wsb + off); off += 2048 * 4;
    int* cur_kk    = (int*)(wsb + off); off += 2048 * 4;
    int* rp_go     = (int*)(wsb + off); off += 2048 * 4;
    int* rp_kk     = (int*)(wsb + off); off += 2048 * 4;
    int* col_go    = (int*)(wsb + off); off += 50048 * 4;
    int* col_kk    = (int*)(wsb + off); off += 20048 * 4;

    hipMemsetAsync(cnt_go, 0, 4 * 2048 * 4, stream);

    int Etot = E_GO + E_KK;
    int histBlocks = (Etot + 255) / 256;

    k_prep<<<1128 + histBlocks, 256, 0, stream>>>(x, xT, xdT, b_dec, bds,
                                                  go_dst, kk_dst, cnt_go, cnt_kk, E_GO, E_KK);
    k_scan2<<<2, 1024, 0, stream>>>(cnt_go, cnt_kk, rp_go, rp_kk);
    k_fill2<<<histBlocks, 256, 0, stream>>>(go_src, go_dst, kk_src, kk_dst, E_GO, E_KK,
                                            rp_go, cur_go, col_go, rp_kk, cur_kk, col_kk);

    k_fuse<<<NKE * NSLAB, 128, 0, stream>>>(xT, rp_go, col_go, W_dec, bds, W_g2k, b_g2k, ke_a);
    k_layer<<<NKE * NSLAB, 128, 0, stream>>>(ke_a, rp_kk, col_kk, W_kk + 0 * 256, b_kk + 0 * 16, ke_b);
    k_layer<<<NKE * NSLAB, 128, 0, stream>>>(ke_b, rp_kk, col_kk, W_kk + 1 * 256, b_kk + 1 * 16, ke_a);
    k_layer<<<NKE * NSLAB, 128, 0, stream>>>(ke_a, rp_kk, col_kk, W_kk + 2 * 256, b_kk + 2 * 16, ke_b);
    k_kescalar<<<NT, 256, 0, stream>>>(ke_b, tissue, w_ke, b_ke, bio_inT);

    // drug tower
    k_gemm<<<dim3(8, 4, 8), 256, 0, stream>>>(xdT, W_drug1, cpart, 512, 256);
    k_red<<<512, 256, 0, stream>>>(cpart, b_drug1, drug1T, 512, 8);
    k_gemm<<<dim3(2, 4, 8), 256, 0, stream>>>(drug1T, W_drug2, cpart, 128, 64);
    k_red<<<128, 256, 0, stream>>>(cpart, b_drug2, drug2T, 128, 8);

    // bio tower
    k_gemm<<<dim3(4, 4, 8), 256, 0, stream>>>(bio_inT, W_bio1, cpart, 256, 64);
    k_red<<<256, 256, 0, stream>>>(cpart, b_bio1, bio1T, 256, 8);
    k_gemm<<<dim3(2, 4, 8), 256, 0, stream>>>(bio1T, W_bio2, cpart, 128, 32);
    k_red<<<128, 256, 0, stream>>>(cpart, b_bio2, bio2T, 128, 8);

    k_final<<<1, 256, 0, stream>>>(bio2T, drug2T, W_pred, b_pred, out);
}

// Round 10
// 221.507 us; speedup vs baseline: 1.0141x; 1.0141x over previous
//
#include <hip/hip_runtime.h>
#include <hip/hip_bf16.h>
#include <cstdint>
#include <cstddef>

#define BATCH 256
#define NGO   8000
#define NKE   2000
#define DD    16
#define XCOLS 10048
#define NDRUG 2048
#define NT    512
#define NSLAB 8
#define SB    32
#define TANH_SCALE 2.885390081777926f   // 2/ln2

__device__ __forceinline__ float tanh_fast(float z) {
    float e = __builtin_amdgcn_exp2f(z * TANH_SCALE);
    float r = __builtin_amdgcn_rcpf(e + 1.0f);
    return fmaf(-2.0f, r, 1.0f);
}

__device__ __forceinline__ float rcp_core(float zp) {
    float e = __builtin_amdgcn_exp2f(zp);
    return __builtin_amdgcn_rcpf(e + 1.0f);
}

__device__ __forceinline__ void add4(float4& a, const float4 b) {
    a.x += b.x; a.y += b.y; a.z += b.z; a.w += b.w;
}

#define RFL(v) __builtin_amdgcn_readfirstlane(v)

// ---------------- CSR scan ----------------
__global__ void k_scan2(const int* __restrict__ cnt_go, const int* __restrict__ cnt_kk,
                        int* __restrict__ rp_go, int* __restrict__ rp_kk) {
    const int* cnt = blockIdx.x ? cnt_kk : cnt_go;
    int* rowptr    = blockIdx.x ? rp_kk  : rp_go;
    __shared__ int s[2048];
    int t = threadIdx.x;
    s[t]        = (t        < NKE) ? cnt[t]        : 0;
    s[t + 1024] = (t + 1024 < NKE) ? cnt[t + 1024] : 0;
    __syncthreads();
    for (int st = 1; st < 2048; st <<= 1) {
        int v0 = (t >= st) ? s[t - st] : 0;
        int v1 = s[t + 1024 - st];
        __syncthreads();
        s[t] += v0; s[t + 1024] += v1;
        __syncthreads();
    }
    if (t == 0) rowptr[0] = 0;
    rowptr[t + 1] = s[t];
    if (t + 1024 < NKE) rowptr[t + 1025] = s[t + 1024];
}

__global__ void k_fill2(const int* __restrict__ gs, const int* __restrict__ gdst,
                        const int* __restrict__ ks, const int* __restrict__ kdst,
                        int Eg, int Ek,
                        const int* __restrict__ rp_go, int* __restrict__ cur_go, int* __restrict__ col_go,
                        const int* __restrict__ rp_kk, int* __restrict__ cur_kk, int* __restrict__ col_kk) {
    int e = blockIdx.x * 256 + threadIdx.x;
    if (e < Eg) {
        int d = gdst[e];
        int p = atomicAdd(&cur_go[d], 1);
        col_go[rp_go[d] + p] = gs[e];
    } else if (e < Eg + Ek) {
        int e2 = e - Eg;
        int d = kdst[e2];
        int p = atomicAdd(&cur_kk[d], 1);
        col_kk[rp_kk[d] + p] = ks[e2];
    }
}

// ---------------- prep: transposes + bd prescale + edge histograms ----------------
__global__ __launch_bounds__(256) void k_prep(const float* __restrict__ x,
                                              float* __restrict__ xT,
                                              float* __restrict__ xdT,
                                              const float* __restrict__ bd,
                                              float* __restrict__ bds,
                                              const int* __restrict__ gdst,
                                              const int* __restrict__ kdst,
                                              int* __restrict__ cnt_go,
                                              int* __restrict__ cnt_kk,
                                              int Eg, int Ek) {
    int bid = blockIdx.x;
    if (bid >= 1128) {
        int e = (bid - 1128) * 256 + threadIdx.x;
        if (e < Eg) atomicAdd(&cnt_go[gdst[e]], 1);
        else if (e < Eg + Ek) atomicAdd(&cnt_kk[kdst[e - Eg]], 1);
        return;
    }
    if (bid >= 628) {
        int i = (bid - 628) * 256 + threadIdx.x;
        bds[i] = bd[i] * TANH_SCALE;
        return;
    }
    __shared__ float tile[64][69];
    int c4 = threadIdx.x & 15, rr = threadIdx.x >> 4;
    int n0, b0;
    bool isgo = bid < 500;
    if (isgo) { n0 = (bid % 125) * 64; b0 = (bid / 125) * 64; }
    else      { int t = bid - 500; n0 = NGO + (t & 31) * 64; b0 = (t >> 5) * 64; }
#pragma unroll
    for (int i = 0; i < 4; i++) {
        int row = rr + i * 16;
        float4 v = *(const float4*)&x[(size_t)(b0 + row) * XCOLS + n0 + c4 * 4];
        tile[row][c4 * 4 + 0] = v.x; tile[row][c4 * 4 + 1] = v.y;
        tile[row][c4 * 4 + 2] = v.z; tile[row][c4 * 4 + 3] = v.w;
    }
    __syncthreads();
#pragma unroll
    for (int i = 0; i < 4; i++) {
        int nrow = rr + i * 16;
        float4 w;
        w.x = tile[c4 * 4 + 0][nrow]; w.y = tile[c4 * 4 + 1][nrow];
        w.z = tile[c4 * 4 + 2][nrow]; w.w = tile[c4 * 4 + 3][nrow];
        if (isgo) {
            w.x *= TANH_SCALE; w.y *= TANH_SCALE; w.z *= TANH_SCALE; w.w *= TANH_SCALE;
            *(float4*)&xT[(size_t)(n0 + nrow) * 256 + b0 + c4 * 4] = w;
        } else {
            *(float4*)&xdT[(size_t)(n0 - NGO + nrow) * 256 + b0 + c4 * 4] = w;
        }
    }
}

// ---------------- fused decode + GO->KE scatter + transform ----------------
__global__ __launch_bounds__(128) void k_fuse(const float* __restrict__ xT,
                                              const int* __restrict__ rowptr,
                                              const int* __restrict__ col,
                                              const float* __restrict__ Wd,
                                              const float* __restrict__ bds,
                                              const float* __restrict__ W,
                                              const float* __restrict__ bias,
                                              float* __restrict__ ke) {
    __shared__ float pre[32 * 17];
    __shared__ float Ws[256];
    __shared__ float bs[16];
    int s = blockIdx.x & 7, n = blockIdx.x >> 3;
    int tid = threadIdx.x;
    Ws[tid] = W[tid]; Ws[tid + 128] = W[tid + 128];
    if (tid < 16) bs[tid] = bias[tid];
    int bloc = tid >> 2, d4 = tid & 3;
    int bglob = s * SB + bloc;

    int e   = RFL(rowptr[n]);
    int end = RFL(rowptr[n + 1]);
    float degF = (float)(end - e);
    float4 acc = make_float4(0, 0, 0, 0);
    for (; e + 3 < end; e += 4) {
        int s0 = RFL(col[e]);
        int s1 = RFL(col[e + 1]);
        int s2 = RFL(col[e + 2]);
        int s3 = RFL(col[e + 3]);
        float xv0 = (xT + (size_t)s0 * 256)[bglob];
        float xv1 = (xT + (size_t)s1 * 256)[bglob];
        float xv2 = (xT + (size_t)s2 * 256)[bglob];
        float xv3 = (xT + (size_t)s3 * 256)[bglob];
        float4 w0 = *(const float4*)(Wd  + (size_t)s0 * 16 + d4 * 4);
        float4 w1 = *(const float4*)(Wd  + (size_t)s1 * 16 + d4 * 4);
        float4 w2 = *(const float4*)(Wd  + (size_t)s2 * 16 + d4 * 4);
        float4 w3 = *(const float4*)(Wd  + (size_t)s3 * 16 + d4 * 4);
        float4 c0 = *(const float4*)(bds + (size_t)s0 * 16 + d4 * 4);
        float4 c1 = *(const float4*)(bds + (size_t)s1 * 16 + d4 * 4);
        float4 c2 = *(const float4*)(bds + (size_t)s2 * 16 + d4 * 4);
        float4 c3 = *(const float4*)(bds + (size_t)s3 * 16 + d4 * 4);
        acc.x += rcp_core(fmaf(xv0, w0.x, c0.x)) + rcp_core(fmaf(xv1, w1.x, c1.x))
               + rcp_core(fmaf(xv2, w2.x, c2.x)) + rcp_core(fmaf(xv3, w3.x, c3.x));
        acc.y += rcp_core(fmaf(xv0, w0.y, c0.y)) + rcp_core(fmaf(xv1, w1.y, c1.y))
               + rcp_core(fmaf(xv2, w2.y, c2.y)) + rcp_core(fmaf(xv3, w3.y, c3.y));
        acc.z += rcp_core(fmaf(xv0, w0.z, c0.z)) + rcp_core(fmaf(xv1, w1.z, c1.z))
               + rcp_core(fmaf(xv2, w2.z, c2.z)) + rcp_core(fmaf(xv3, w3.z, c3.z));
        acc.w += rcp_core(fmaf(xv0, w0.w, c0.w)) + rcp_core(fmaf(xv1, w1.w, c1.w))
               + rcp_core(fmaf(xv2, w2.w, c2.w)) + rcp_core(fmaf(xv3, w3.w, c3.w));
    }
    for (; e < end; ++e) {
        int s0 = RFL(col[e]);
        float xv0 = (xT + (size_t)s0 * 256)[bglob];
        float4 w0 = *(const float4*)(Wd  + (size_t)s0 * 16 + d4 * 4);
        float4 c0 = *(const float4*)(bds + (size_t)s0 * 16 + d4 * 4);
        acc.x += rcp_core(fmaf(xv0, w0.x, c0.x));
        acc.y += rcp_core(fmaf(xv0, w0.y, c0.y));
        acc.z += rcp_core(fmaf(xv0, w0.z, c0.z));
        acc.w += rcp_core(fmaf(xv0, w0.w, c0.w));
    }
    pre[bloc * 17 + d4 * 4 + 0] = fmaf(-2.0f, acc.x, degF);
    pre[bloc * 17 + d4 * 4 + 1] = fmaf(-2.0f, acc.y, degF);
    pre[bloc * 17 + d4 * 4 + 2] = fmaf(-2.0f, acc.z, degF);
    pre[bloc * 17 + d4 * 4 + 3] = fmaf(-2.0f, acc.w, degF);
    __syncthreads();

    float4 o;
    float* op = &o.x;
#pragma unroll
    for (int q = 0; q < 4; q++) {
        int dp = d4 * 4 + q;
        float a = bs[dp];
#pragma unroll
        for (int d = 0; d < 16; d++) a = fmaf(pre[bloc * 17 + d], Ws[d * 16 + dp], a);
        op[q] = tanh_fast(a);
    }
    *(float4*)&ke[((size_t)s * NKE + n) * 512 + bloc * 16 + d4 * 4] = o;
}

// ---------------- KE-KE layer ----------------
__global__ __launch_bounds__(128) void k_layer(const float* __restrict__ kin,
                                               const int* __restrict__ rowptr,
                                               const int* __restrict__ col,
                                               const float* __restrict__ W,
                                               const float* __restrict__ bias,
                                               float* __restrict__ kout) {
    __shared__ float pre[32 * 17];
    __shared__ float Ws[256];
    __shared__ float bs[16];
    int s = blockIdx.x & 7, n = blockIdx.x >> 3;
    int tid = threadIdx.x;
    Ws[tid] = W[tid]; Ws[tid + 128] = W[tid + 128];
    if (tid < 16) bs[tid] = bias[tid];
    int bloc = tid >> 2, d4 = tid & 3;
    const float* slab = kin + (size_t)s * NKE * 512;

    float4 acc = *(const float4*)(slab + (size_t)n * 512 + tid * 4);
    int e   = RFL(rowptr[n]);
    int end = RFL(rowptr[n + 1]);
    for (; e + 3 < end; e += 4) {
        int c0 = RFL(col[e]), c1 = RFL(col[e + 1]), c2 = RFL(col[e + 2]), c3 = RFL(col[e + 3]);
        float4 v0 = *(const float4*)(slab + (size_t)c0 * 512 + tid * 4);
        float4 v1 = *(const float4*)(slab + (size_t)c1 * 512 + tid * 4);
        float4 v2 = *(const float4*)(slab + (size_t)c2 * 512 + tid * 4);
        float4 v3 = *(const float4*)(slab + (size_t)c3 * 512 + tid * 4);
        add4(acc, v0); add4(acc, v1); add4(acc, v2); add4(acc, v3);
    }
    for (; e < end; ++e) {
        int c0 = RFL(col[e]);
        float4 v0 = *(const float4*)(slab + (size_t)c0 * 512 + tid * 4);
        add4(acc, v0);
    }
    pre[bloc * 17 + d4 * 4 + 0] = acc.x;
    pre[bloc * 17 + d4 * 4 + 1] = acc.y;
    pre[bloc * 17 + d4 * 4 + 2] = acc.z;
    pre[bloc * 17 + d4 * 4 + 3] = acc.w;
    __syncthreads();

    float4 o;
    float* op = &o.x;
#pragma unroll
    for (int q = 0; q < 4; q++) {
        int dp = d4 * 4 + q;
        float a = bs[dp];
#pragma unroll
        for (int d = 0; d < 16; d++) a = fmaf(pre[bloc * 17 + d], Ws[d * 16 + dp], a);
        op[q] = tanh_fast(a);
    }
    *(float4*)&kout[(size_t)s * NKE * 512 + (size_t)n * 512 + bloc * 16 + d4 * 4] = o;
}

// ---------------- device bodies for merged launches ----------------
__device__ __forceinline__ void dev_kescalar(int t, const float* __restrict__ ke,
                                             const int* __restrict__ tissue,
                                             const float* __restrict__ wke,
                                             const float* __restrict__ bke,
                                             float* __restrict__ bioT) {
    int b = threadIdx.x;
    int n = RFL(tissue[t]);
    int s = b >> 5, bloc = b & 31;
    const float4* kp = (const float4*)&ke[((size_t)s * NKE + n) * 512 + bloc * 16];
    const float4* wp = (const float4*)wke;
    float4 k0 = kp[0], k1 = kp[1], k2 = kp[2], k3 = kp[3];
    float4 w0 = wp[0], w1 = wp[1], w2 = wp[2], w3 = wp[3];
    float acc = bke[0];
    acc += k0.x * w0.x + k0.y * w0.y + k0.z * w0.z + k0.w * w0.w;
    acc += k1.x * w1.x + k1.y * w1.y + k1.z * w1.z + k1.w * w1.w;
    acc += k2.x * w2.x + k2.y * w2.y + k2.z * w2.z + k2.w * w2.w;
    acc += k3.x * w3.x + k3.y * w3.y + k3.z * w3.z + k3.w * w3.w;
    bioT[t * 256 + b] = tanh_fast(acc);
}

__device__ __forceinline__ void dev_gemm(int bid, const float* __restrict__ A,
                                         const float* __restrict__ W,
                                         float* __restrict__ Cpart,
                                         int N, int Kper, int gx,
                                         float (*As)[68], float (*Ws)[68]) {
    int tid = threadIdx.x;
    int tx = tid & 15, ty = tid >> 4;
    int jx = bid % gx;
    int by = (bid / gx) & 3;
    int ks = bid / (gx * 4);
    int jt = jx * 64, bt = by * 64;
    int k0 = ks * Kper;

    float acc[4][4];
#pragma unroll
    for (int i = 0; i < 4; i++)
#pragma unroll
        for (int j = 0; j < 4; j++) acc[i][j] = 0.0f;

    for (int kc = 0; kc < Kper; kc += 32) {
#pragma unroll
        for (int i = 0; i < 8; i++) {
            int idx = tid + i * 256;
            int kk = idx >> 6, cc = idx & 63;
            As[kk][cc] = A[(size_t)(k0 + kc + kk) * 256 + bt + cc];
            Ws[kk][cc] = W[(size_t)(k0 + kc + kk) * N + jt + cc];
        }
        __syncthreads();
#pragma unroll 8
        for (int kk = 0; kk < 32; kk++) {
            float4 a = *(const float4*)&As[kk][tx * 4];
            float4 w = *(const float4*)&Ws[kk][ty * 4];
            acc[0][0] = fmaf(w.x, a.x, acc[0][0]); acc[0][1] = fmaf(w.x, a.y, acc[0][1]);
            acc[0][2] = fmaf(w.x, a.z, acc[0][2]); acc[0][3] = fmaf(w.x, a.w, acc[0][3]);
            acc[1][0] = fmaf(w.y, a.x, acc[1][0]); acc[1][1] = fmaf(w.y, a.y, acc[1][1]);
            acc[1][2] = fmaf(w.y, a.z, acc[1][2]); acc[1][3] = fmaf(w.y, a.w, acc[1][3]);
            acc[2][0] = fmaf(w.z, a.x, acc[2][0]); acc[2][1] = fmaf(w.z, a.y, acc[2][1]);
            acc[2][2] = fmaf(w.z, a.z, acc[2][2]); acc[2][3] = fmaf(w.z, a.w, acc[2][3]);
            acc[3][0] = fmaf(w.w, a.x, acc[3][0]); acc[3][1] = fmaf(w.w, a.y, acc[3][1]);
            acc[3][2] = fmaf(w.w, a.z, acc[3][2]); acc[3][3] = fmaf(w.w, a.w, acc[3][3]);
        }
        __syncthreads();
    }
#pragma unroll
    for (int jy = 0; jy < 4; jy++) {
        int j = jt + ty * 4 + jy;
        float4 v = make_float4(acc[jy][0], acc[jy][1], acc[jy][2], acc[jy][3]);
        *(float4*)&Cpart[((size_t)ks * N + j) * 256 + bt + tx * 4] = v;
    }
}

__device__ __forceinline__ void dev_red(int j, const float* __restrict__ Cpart,
                                        const float* __restrict__ bias,
                                        float* __restrict__ C, int N, int S) {
    int b = threadIdx.x;
    float acc = bias[j];
    for (int s = 0; s < S; s++) acc += Cpart[((size_t)s * N + j) * 256 + b];
    C[j * 256 + b] = fmaxf(acc, 0.0f);
}

// ---------------- merged launches ----------------
// blocks [0, nk): kescalar; blocks [nk, nk+gemmBlocks): gemm
__global__ __launch_bounds__(256) void k_kg(const float* __restrict__ ke,
                                            const int* __restrict__ tissue,
                                            const float* __restrict__ wke,
                                            const float* __restrict__ bke,
                                            float* __restrict__ bioT,
                                            const float* __restrict__ A,
                                            const float* __restrict__ W,
                                            float* __restrict__ Cpart,
                                            int N, int Kper, int gx, int nk) {
    __shared__ float As[32][68];
    __shared__ float Ws[32][68];
    int bid = blockIdx.x;
    if (bid < nk) dev_kescalar(bid, ke, tissue, wke, bke, bioT);
    else          dev_gemm(bid - nk, A, W, Cpart, N, Kper, gx, As, Ws);
}

// blocks [0, gB): gemm job; blocks [gB, gB+RN): red job
__global__ __launch_bounds__(256) void k_gr(const float* __restrict__ A,
                                            const float* __restrict__ W,
                                            float* __restrict__ Cpart,
                                            int N, int Kper, int gx, int gB,
                                            const float* __restrict__ Rcp,
                                            const float* __restrict__ Rbias,
                                            float* __restrict__ RC, int RN, int RS) {
    __shared__ float As[32][68];
    __shared__ float Ws[32][68];
    int bid = blockIdx.x;
    if (bid < gB) dev_gemm(bid, A, W, Cpart, N, Kper, gx, As, Ws);
    else          dev_red(bid - gB, Rcp, Rbias, RC, RN, RS);
}

__global__ __launch_bounds__(256) void k_red(const float* __restrict__ Cpart,
                                             const float* __restrict__ bias,
                                             float* __restrict__ C, int N, int S) {
    dev_red(blockIdx.x, Cpart, bias, C, N, S);
}

// ---------------- final head ----------------
__global__ __launch_bounds__(256) void k_final(const float* __restrict__ bio2T,
                                               const float* __restrict__ drug2T,
                                               const float* __restrict__ Wp,
                                               const float* __restrict__ bp,
                                               float* __restrict__ out) {
    int b = threadIdx.x;
    float acc = bp[0];
#pragma unroll 8
    for (int i = 0; i < 128; i++) acc = fmaf(bio2T[i * 256 + b], Wp[i], acc);
#pragma unroll 8
    for (int i = 0; i < 128; i++) acc = fmaf(drug2T[i * 256 + b], Wp[128 + i], acc);
    out[b] = acc;
}

extern "C" void kernel_launch(void* const* d_in, const int* in_sizes, int n_in,
                              void* d_out, int out_size, void* d_ws, size_t ws_size,
                              hipStream_t stream) {
    const float* x       = (const float*)d_in[0];
    const int*   go_src  = (const int*)d_in[1];
    const int*   go_dst  = (const int*)d_in[2];
    const int*   kk_src  = (const int*)d_in[3];
    const int*   kk_dst  = (const int*)d_in[4];
    const int*   tissue  = (const int*)d_in[5];
    const float* W_dec   = (const float*)d_in[6];
    const float* b_dec   = (const float*)d_in[7];
    const float* W_g2k   = (const float*)d_in[8];
    const float* b_g2k   = (const float*)d_in[9];
    const float* W_kk    = (const float*)d_in[10];
    const float* b_kk    = (const float*)d_in[11];
    const float* w_ke    = (const float*)d_in[12];
    const float* b_ke    = (const float*)d_in[13];
    const float* W_bio1  = (const float*)d_in[14];
    const float* b_bio1  = (const float*)d_in[15];
    const float* W_bio2  = (const float*)d_in[16];
    const float* b_bio2  = (const float*)d_in[17];
    const float* W_drug1 = (const float*)d_in[18];
    const float* b_drug1 = (const float*)d_in[19];
    const float* W_drug2 = (const float*)d_in[20];
    const float* b_drug2 = (const float*)d_in[21];
    const float* W_pred  = (const float*)d_in[22];
    const float* b_pred  = (const float*)d_in[23];
    float* out = (float*)d_out;

    const int E_GO = in_sizes[1];
    const int E_KK = in_sizes[3];

    char* wsb = (char*)d_ws;
    size_t off = 0;
    float* xT      = (float*)(wsb + off); off += (size_t)NGO * 256 * 4;
    float* ke_a    = (float*)(wsb + off); off += (size_t)NSLAB * NKE * 512 * 4;
    float* ke_b    = (float*)(wsb + off); off += (size_t)NSLAB * NKE * 512 * 4;
    float* bio_inT = (float*)(wsb + off); off += (size_t)NT * 256 * 4;
    float* bio1T   = (float*)(wsb + off); off += (size_t)256 * 256 * 4;
    float* bio2T   = (float*)(wsb + off); off += (size_t)128 * 256 * 4;
    float* xdT     = (float*)(wsb + off); off += (size_t)NDRUG * 256 * 4;
    float* drug1T  = (float*)(wsb + off); off += (size_t)512 * 256 * 4;
    float* drug2T  = (float*)(wsb + off); off += (size_t)128 * 256 * 4;
    float* bds     = (float*)(wsb + off); off += (size_t)NGO * 16 * 4;
    float* cp_d1   = (float*)(wsb + off); off += (size_t)8 * 512 * 256 * 4;
    float* cp_b1   = (float*)(wsb + off); off += (size_t)8 * 256 * 256 * 4;
    float* cp_d2   = (float*)(wsb + off); off += (size_t)8 * 128 * 256 * 4;
    float* cp_b2   = (float*)(wsb + off); off += (size_t)8 * 128 * 256 * 4;
    int* cnt_go    = (int*)(wsb + off); off += 2048 * 4;
    int* cur_go    = (int*)(wsb + off); off += 2048 * 4;
    int* cnt_kk    = (int*)(wsb + off); off += 2048 * 4;
    int* cur_kk    = (int*)(wsb + off); off += 2048 * 4;
    int* rp_go     = (int*)(wsb + off); off += 2048 * 4;
    int* rp_kk     = (int*)(wsb + off); off += 2048 * 4;
    int* col_go    = (int*)(wsb + off); off += 50048 * 4;
    int* col_kk    = (int*)(wsb + off); off += 20048 * 4;

    hipMemsetAsync(cnt_go, 0, 4 * 2048 * 4, stream);

    int Etot = E_GO + E_KK;
    int histBlocks = (Etot + 255) / 256;

    k_prep<<<1128 + histBlocks, 256, 0, stream>>>(x, xT, xdT, b_dec, bds,
                                                  go_dst, kk_dst, cnt_go, cnt_kk, E_GO, E_KK);
    k_scan2<<<2, 1024, 0, stream>>>(cnt_go, cnt_kk, rp_go, rp_kk);
    k_fill2<<<histBlocks, 256, 0, stream>>>(go_src, go_dst, kk_src, kk_dst, E_GO, E_KK,
                                            rp_go, cur_go, col_go, rp_kk, cur_kk, col_kk);

    k_fuse<<<NKE * NSLAB, 128, 0, stream>>>(xT, rp_go, col_go, W_dec, bds, W_g2k, b_g2k, ke_a);
    k_layer<<<NKE * NSLAB, 128, 0, stream>>>(ke_a, rp_kk, col_kk, W_kk + 0 * 256, b_kk + 0 * 16, ke_b);
    k_layer<<<NKE * NSLAB, 128, 0, stream>>>(ke_b, rp_kk, col_kk, W_kk + 1 * 256, b_kk + 1 * 16, ke_a);
    k_layer<<<NKE * NSLAB, 128, 0, stream>>>(ke_a, rp_kk, col_kk, W_kk + 2 * 256, b_kk + 2 * 16, ke_b);

    // merged tower schedule (drug ∥ bio), all dependencies cross-launch:
    // [kescalar + gemm_d1]  kesc: ke_b -> bio_inT ; gd1: xdT -> cp_d1 (N=512,Kper=256,gx=8, 256 blocks)
    k_kg<<<NT + 256, 256, 0, stream>>>(ke_b, tissue, w_ke, b_ke, bio_inT,
                                       xdT, W_drug1, cp_d1, 512, 256, 8, NT);
    // [gemm_b1 + red_d1]  gb1: bio_inT -> cp_b1 (N=256,Kper=64,gx=4, 128 blocks); rd1: cp_d1 -> drug1T (512, S=8)
    k_gr<<<128 + 512, 256, 0, stream>>>(bio_inT, W_bio1, cp_b1, 256, 64, 4, 128,
                                        cp_d1, b_drug1, drug1T, 512, 8);
    // [gemm_d2 + red_b1]  gd2: drug1T -> cp_d2 (N=128,Kper=64,gx=2, 64 blocks); rb1: cp_b1 -> bio1T (256, S=8)
    k_gr<<<64 + 256, 256, 0, stream>>>(drug1T, W_drug2, cp_d2, 128, 64, 2, 64,
                                       cp_b1, b_bio1, bio1T, 256, 8);
    // [gemm_b2 + red_d2]  gb2: bio1T -> cp_b2 (N=128,Kper=32,gx=2, 64 blocks); rd2: cp_d2 -> drug2T (128, S=8)
    k_gr<<<64 + 128, 256, 0, stream>>>(bio1T, W_bio2, cp_b2, 128, 32, 2, 64,
                                       cp_d2, b_drug2, drug2T, 128, 8);
    // [red_b2]
    k_red<<<128, 256, 0, stream>>>(cp_b2, b_bio2, bio2T, 128, 8);

    k_final<<<1, 256, 0, stream>>>(bio2T, drug2T, W_pred, b_pred, out);
}